// Round 3
// baseline (676.637 us; speedup 1.0000x reference)
//
#include <hip/hip_runtime.h>
#include <hip/hip_bf16.h>

#define DIMK 3
#define NPTS 30
#define KK   181
#define PP   24360
#define DEMB 190
#define VLD  192   // padded vec row stride (bf16 elements)
#define SNP  24576 // padded row length = 16*1536 (sort rows AND sm2T stride)

typedef __attribute__((ext_vector_type(8))) short bf16x8;
typedef __attribute__((ext_vector_type(4))) float f32x4;
typedef __attribute__((ext_vector_type(2))) __fp16 h2;
typedef __attribute__((ext_vector_type(4))) ushort u16x4;

__device__ __forceinline__ ushort f2bf(float f) {
    unsigned u = __float_as_uint(f);
    u += 0x7FFFu + ((u >> 16) & 1u);
    return (ushort)(u >> 16);
}

// ---------------------------------------------------------------------------
// Kernel 1: per-permutation inner embed -> vec (PP x VLD, bf16)
// [frozen r23: packed-f16 pair sorting, 63.3 us, VALU-bound]
// ---------------------------------------------------------------------------
__global__ __launch_bounds__(1024, 2) void k_inner(
    const float* __restrict__ M,      // 3 x 30
    const float* __restrict__ Ws_in,  // 181 x 3
    const float* __restrict__ Wd_in,  // 181 x 27
    const float* __restrict__ Wout,   // 181 x 190
    ushort* __restrict__ Abf,         // 192 x 192 bf16 out
    ushort* __restrict__ vec)         // PP x VLD (bf16)
{
    __shared__ float Gs[NPTS * 32];
    __shared__ float WsS[192 * 3];
    __shared__ float WdS[192 * 28];

    const int tid = threadIdx.x;

    {
        int gid = blockIdx.x * 1024 + tid;
        if (gid < 192 * 192) {
            int k = gid / 192, d = gid - k * 192;
            Abf[gid] = (k < KK && d < DEMB) ? f2bf(Wout[k * DEMB + d]) : (ushort)0;
        }
    }

    for (int i = tid; i < 192 * 3; i += 1024) WsS[i] = (i < KK * 3) ? Ws_in[i] : 0.f;
    for (int i = tid; i < 192 * 28; i += 1024) {
        int k = i / 28, m = i - k * 28;
        WdS[i] = (k < KK && m < 27) ? Wd_in[k * 27 + m] : 0.f;
    }
    for (int e = tid; e < NPTS * 32; e += 1024) {
        int a = e >> 5, b = e & 31;
        Gs[e] = (b < NPTS)
            ? (M[a] * M[b] + M[NPTS + a] * M[NPTS + b] + M[2 * NPTS + a] * M[2 * NPTS + b])
            : 0.f;
    }
    __syncthreads();

    const int wave = tid >> 6;
    const int lane = tid & 63;
    const int wid = blockIdx.x * 16 + wave;   // 0..8191
    const int chunk = wid % 3;
    const int pstream = wid / 3;              // 0..2730
    const int nstream = (chunk == 2) ? 2730 : 2731;
    const int k = chunk * 64 + lane;

    const float INF = __builtin_inff();
    const bool kvalid = (k < KK);
    const float w0 = WsS[k * 3 + 0];
    const float w1 = WsS[k * 3 + 1];
    const float w2 = WsS[k * 3 + 2];
    const float* wd = WdS + k * 28;

    const int NPAIR = PP / 2;   // 12180

    for (int t = pstream; t < NPAIR; t += nstream) {
        const int p0 = 2 * t;
        // decode p0; p1 = p0+1 always shares i0,i1 (i2 of p0 is even, <=26)
        int i0 = p0 / 812;            // 812 = 29*28
        int r  = p0 - i0 * 812;
        int i1 = r / 28;
        int i2 = r - i1 * 28;
        int c0 = i0;
        int c1 = i1 + (i1 >= c0 ? 1 : 0);
        int lo = min(c0, c1), hi = max(c0, c1);
        int c2a = i2;
        if (c2a >= lo) c2a++;
        if (c2a >= hi) c2a++;
        int c2b = i2 + 1;
        if (c2b >= lo) c2b++;
        if (c2b >= hi) c2b++;

        ushort* vrow0 = vec + (long)p0 * VLD;
        ushort* vrow1 = vrow0 + VLD;

        if (chunk == 0 && lane < 9) {
            int i = lane / 3, j = lane % 3;
            int cia = (i == 0) ? c0 : ((i == 1) ? c1 : c2a);
            int cja = (j == 0) ? c0 : ((j == 1) ? c1 : c2a);
            vrow0[lane] = f2bf(Gs[(cia << 5) + cja]);
            int cib = (i == 0) ? c0 : ((i == 1) ? c1 : c2b);
            int cjb = (j == 0) ? c0 : ((j == 1) ? c1 : c2b);
            vrow1[lane] = f2bf(Gs[(cib << 5) + cjb]);
        }

        const float* g0 = Gs + (c0 << 5);
        const float* g1 = Gs + (c1 << 5);
        const float* ga = Gs + (c2a << 5);
        const float* gb = Gs + (c2b << 5);
        const unsigned basem = (1u << c0) | (1u << c1);
        const unsigned maska = basem | (1u << c2a);
        const unsigned maskb = basem | (1u << c2b);

        h2 s[30];
#pragma unroll
        for (int q = 0; q < 8; ++q) {
            float4 x0 = *(const float4*)&g0[q * 4];
            float4 x1 = *(const float4*)&g1[q * 4];
            float4 xa = *(const float4*)&ga[q * 4];
            float4 xb = *(const float4*)&gb[q * 4];
            int j0 = q * 4;
            if (j0 + 0 < NPTS) {
                float c = w0 * x0.x + w1 * x1.x;
                float va = w2 * xa.x + c;
                float vb = w2 * xb.x + c;
                va = ((maska >> (j0 + 0)) & 1u) ? INF : va;
                vb = ((maskb >> (j0 + 0)) & 1u) ? INF : vb;
                s[j0 + 0] = __builtin_amdgcn_cvt_pkrtz(va, vb);
            }
            if (j0 + 1 < NPTS) {
                float c = w0 * x0.y + w1 * x1.y;
                float va = w2 * xa.y + c;
                float vb = w2 * xb.y + c;
                va = ((maska >> (j0 + 1)) & 1u) ? INF : va;
                vb = ((maskb >> (j0 + 1)) & 1u) ? INF : vb;
                s[j0 + 1] = __builtin_amdgcn_cvt_pkrtz(va, vb);
            }
            if (j0 + 2 < NPTS) {
                float c = w0 * x0.z + w1 * x1.z;
                float va = w2 * xa.z + c;
                float vb = w2 * xb.z + c;
                va = ((maska >> (j0 + 2)) & 1u) ? INF : va;
                vb = ((maskb >> (j0 + 2)) & 1u) ? INF : vb;
                s[j0 + 2] = __builtin_amdgcn_cvt_pkrtz(va, vb);
            }
            if (j0 + 3 < NPTS) {
                float c = w0 * x0.w + w1 * x1.w;
                float va = w2 * xa.w + c;
                float vb = w2 * xb.w + c;
                va = ((maska >> (j0 + 3)) & 1u) ? INF : va;
                vb = ((maskb >> (j0 + 3)) & 1u) ? INF : vb;
                s[j0 + 3] = __builtin_amdgcn_cvt_pkrtz(va, vb);
            }
        }

        // Batcher odd-even mergesort, pruned, packed pairs
#pragma unroll
        for (int pw = 1; pw < 32; pw <<= 1) {
#pragma unroll
            for (int kk = pw; kk >= 1; kk >>= 1) {
#pragma unroll
                for (int j = kk % pw; j + kk < 32; j += 2 * kk) {
#pragma unroll
                    for (int i = 0; i < kk; ++i) {
                        int a = i + j, b = i + j + kk;
                        if (a / (pw * 2) == b / (pw * 2) && b < 30
                            && !(pw == 16 && a == 27)) {
                            h2 x = s[a], y = s[b];
                            s[a] = __builtin_elementwise_min(x, y);
                            s[b] = __builtin_elementwise_max(x, y);
                        }
                    }
                }
            }
        }

        if (kvalid) {
            float emb0 = 0.f, emb1 = 0.f;
#pragma unroll
            for (int j = 0; j < 24; j += 4) {
                float4 w4 = *(const float4*)&wd[j];
                emb0 += w4.x * (float)s[j + 0].x + w4.y * (float)s[j + 1].x
                      + w4.z * (float)s[j + 2].x + w4.w * (float)s[j + 3].x;
                emb1 += w4.x * (float)s[j + 0].y + w4.y * (float)s[j + 1].y
                      + w4.z * (float)s[j + 2].y + w4.w * (float)s[j + 3].y;
            }
            {
                float4 w4 = *(const float4*)&wd[24];
                emb0 += w4.x * (float)s[24].x + w4.y * (float)s[25].x
                      + w4.z * (float)s[26].x;
                emb1 += w4.x * (float)s[24].y + w4.y * (float)s[25].y
                      + w4.z * (float)s[26].y;
            }
            vrow0[9 + k] = f2bf(emb0);
            vrow1[9 + k] = f2bf(emb1);
        } else if (k < 183) {
            vrow0[9 + k] = 0;
            vrow1[9 + k] = 0;
        }
    }
}

// ---------------------------------------------------------------------------
// Kernel 2 (r24): sm2TP[k][p] via bf16 MFMA.
// - vec tile (64 rows x 384B) staged to LDS with linear coalesced copies,
//   padded to 400B rows (bank stride 4 -> 2-way, free).
// - MFMA operands SWAPPED vs r20: mfma(vecfrag, Abffrag) makes D's reg axis
//   the p axis -> each lane's 4 accs are 4 consecutive p in ONE kg row ->
//   single packed 8B ushort4 store (was 4 scalar 2B scatters).
// - also zeroes out[] for k_hist's atomics.
// ---------------------------------------------------------------------------
__global__ __launch_bounds__(256) void k_gemm(
    const ushort* __restrict__ vecB,  // PP x 192 bf16
    const ushort* __restrict__ Abf,   // 192 x 192 bf16
    ushort* __restrict__ sm2TP,       // 181 x SNP u16 encoded keys
    float* __restrict__ out)          // 181 (zeroed here)
{
    __shared__ ushort vs[64 * 200];   // 400B-padded rows, 25.6 KB

    const int tid  = threadIdx.x;
    const int bid  = blockIdx.x;
    const int tile = bid >> 2;        // p-tile (64 p's)
    const int qtr  = bid & 3;         // kt quarter: 3 kt each
    const int wave = tid >> 6;
    const int lane = tid & 63;
    const int n = lane & 15;
    const int quad = lane >> 4;

    if (bid == 0 && tid < KK) out[tid] = 0.f;

    // stage 64 rows x 384B = 24KB (reads past vecB end for pad tiles land in
    // workspace -> valid memory, values discarded via pad encode)
    {
        const char* src = (const char*)(vecB + (size_t)tile * 64 * VLD);
#pragma unroll
        for (int it = 0; it < 6; ++it) {
            int byte = (it * 256 + tid) * 16;
            int row = byte / 384;
            int col = byte - row * 384;
            bf16x8 d = *(const bf16x8*)(src + byte);
            *(bf16x8*)((char*)vs + row * 400 + col) = d;
        }
    }
    __syncthreads();

    // A fragments: vec row (wave*16 + n), 6 k-chunks from padded LDS
    bf16x8 afrag[6];
    {
        const char* base = (const char*)vs + (wave * 16 + n) * 400;
#pragma unroll
        for (int kc = 0; kc < 6; ++kc)
            afrag[kc] = *(const bf16x8*)(base + kc * 64 + quad * 16);
    }

    const int pb = tile * 64 + wave * 16 + quad * 4;  // lane's 4 consecutive p

#pragma unroll
    for (int i = 0; i < 3; ++i) {
        const int kt = qtr * 3 + i;
        const int kg = kt * 16 + n;
        f32x4 acc = {0.f, 0.f, 0.f, 0.f};
        const ushort* arow = Abf + kg * 192;
#pragma unroll
        for (int kc = 0; kc < 6; ++kc) {
            bf16x8 bfrag = *(const bf16x8*)&arow[kc * 32 + quad * 8];
            acc = __builtin_amdgcn_mfma_f32_16x16x32_bf16(afrag[kc], bfrag, acc, 0, 0, 0);
        }
        if (kg < KK) {
            u16x4 st;
#pragma unroll
            for (int r = 0; r < 4; ++r) {
                int p = pb + r;
                unsigned e;
                if (p < PP) {
                    unsigned u = __float_as_uint(acc[r]);
                    u = (u & 0x80000000u) ? ~u : (u | 0x80000000u);
                    e = (u + 0x8000u) >> 16;     // RTN 16-bit monotone key
                } else {
                    e = 0xFFFFu;                 // pad sorts strictly last
                }
                st[r] = (ushort)e;
            }
            *(u16x4*)&sm2TP[(size_t)kg * SNP + pb] = st;  // 8B aligned (pb%4==0)
        }
    }
}

// ---------------------------------------------------------------------------
// Kernel 3 (r24): histogram-CDF replaces radix scatter. Runs of equal 16-bit
// keys contribute val(key) * sum(wrow[run]) regardless of intra-run order, so
// exact ranks are unnecessary: per k, histogram keys into 64K bins (4 blocks
// x 16384 bins = 64KB LDS), exclusive-scan, accumulate val * contiguous wrow
// segment per nonzero bin. Identical result to the r19 radix sort (same key
// quantization, same tie semantics, pads capped at PP). atomicAdd merges the
// 4 window-blocks into out[k] (zeroed in k_gemm).
// ---------------------------------------------------------------------------
#define HB 16384

__global__ __launch_bounds__(1024, 2) void k_hist(
    const ushort* __restrict__ sm2TP,    // 181 x SNP u16 keys (padded)
    const float* __restrict__ WdOut,     // 181 x PP
    float* __restrict__ out)             // 181 (accumulated)
{
    __shared__ unsigned hist[HB];        // 64 KiB
    __shared__ unsigned wred[16];
    __shared__ unsigned wscan[16];
    __shared__ float fred[16];

    const int tid  = threadIdx.x;
    const int wave = tid >> 6;
    const int lane = tid & 63;
    const int k = blockIdx.x >> 2;
    const int q = blockIdx.x & 3;
    const unsigned base = (unsigned)q * HB;

    const ushort* rowU = sm2TP + (size_t)k * SNP;
    const float* wrow  = WdOut + (size_t)k * PP;

    for (int i = tid; i < HB; i += 1024) hist[i] = 0u;
    __syncthreads();

    // histogram this block's key window; count keys below the window
    unsigned below = 0;
    for (int j = 0; j < 24; ++j) {
        unsigned u = rowU[tid + j * 1024];
        below += (u < base) ? 1u : 0u;
        unsigned rel = u - base;
        if (rel < (unsigned)HB) atomicAdd(&hist[rel], 1u);
    }
    {
        unsigned b = below;
#pragma unroll
        for (int off = 32; off > 0; off >>= 1)
            b += (unsigned)__shfl_down((int)b, off, 64);
        if (lane == 0) wred[wave] = b;
    }
    __syncthreads();   // hist complete + wred visible
    unsigned below_tot = 0;
#pragma unroll
    for (int w = 0; w < 16; ++w) below_tot += wred[w];

    // per-thread exclusive scan over its 16 bins
    unsigned loc[16];
    unsigned tsum = 0;
#pragma unroll
    for (int bq = 0; bq < 16; ++bq) {
        loc[bq] = tsum;
        tsum += hist[tid * 16 + bq];
    }
    // wave inclusive scan of tsum
    unsigned inc = tsum;
#pragma unroll
    for (int off = 1; off < 64; off <<= 1) {
        unsigned o = (unsigned)__shfl_up((int)inc, off, 64);
        if (lane >= off) inc += o;
    }
    if (lane == 63) wscan[wave] = inc;
    __syncthreads();
    unsigned wbase = 0;
#pragma unroll
    for (int w = 0; w < 16; ++w) wbase += (w < wave) ? wscan[w] : 0u;

    unsigned r0 = below_tot + wbase + (inc - tsum);

    // fused dot: each nonzero bin consumes a contiguous wrow segment
    float acc = 0.f;
#pragma unroll
    for (int bq = 0; bq < 16; ++bq) {
        unsigned c = hist[tid * 16 + bq];
        if (c) {
            unsigned key = base + (unsigned)tid * 16 + bq;
            unsigned raw16 = (key & 0x8000u) ? (key & 0x7FFFu) : ((~key) & 0xFFFFu);
            float val = __uint_as_float(raw16 << 16);
            unsigned r = r0 + loc[bq];
            unsigned cl = (r < (unsigned)PP) ? min(c, (unsigned)PP - r) : 0u;
            for (unsigned j = 0; j < cl; ++j)
                acc += wrow[r + j] * val;
        }
    }

#pragma unroll
    for (int off = 32; off > 0; off >>= 1)
        acc += __shfl_down(acc, off, 64);
    if (lane == 0) fred[wave] = acc;
    __syncthreads();
    if (tid == 0) {
        float t = 0.f;
#pragma unroll
        for (int w = 0; w < 16; ++w) t += fred[w];
        atomicAdd(&out[k], t);
    }
}

// ---------------------------------------------------------------------------
extern "C" void kernel_launch(void* const* d_in, const int* in_sizes, int n_in,
                              void* d_out, int out_size, void* d_ws, size_t ws_size,
                              hipStream_t stream) {
    const float* M      = (const float*)d_in[0];
    const float* Ws_in  = (const float*)d_in[1];
    const float* Wd_in  = (const float*)d_in[2];
    const float* Ws_out = (const float*)d_in[3];
    const float* Wd_out = (const float*)d_in[4];
    float* out = (float*)d_out;

    // workspace layout (18.4 MB):
    // [0, 9.36 MB):    vecB (PP x 192 bf16)
    // [9.36, 18.26):   sm2TP (181 x SNP u16 keys)
    // [18.26, +74KB):  Abf (192 x 192 bf16)
    char* ws = (char*)d_ws;
    ushort* vecB  = (ushort*)ws;
    ushort* sm2TP = (ushort*)(ws + (size_t)PP * VLD * 2);
    ushort* Abf   = (ushort*)(ws + (size_t)PP * VLD * 2 + (size_t)KK * SNP * 2);

    k_inner<<<512, 1024, 0, stream>>>(M, Ws_in, Wd_in, Ws_out, Abf, vecB);

    k_gemm<<<(SNP / 64) * 4, 256, 0, stream>>>(vecB, Abf, sm2TP, out);

    k_hist<<<KK * 4, 1024, 0, stream>>>(sm2TP, Wd_out, out);
}

// Round 4
// 201.772 us; speedup vs baseline: 3.3535x; 3.3535x over previous
//
#include <hip/hip_runtime.h>
#include <hip/hip_bf16.h>

#define DIMK 3
#define NPTS 30
#define KK   181
#define PP   24360
#define DEMB 190
#define VLD  192   // padded vec row stride (bf16 elements)
#define SNP  24576 // padded row length = 16*1536 (sort rows AND sm2T stride)

typedef __attribute__((ext_vector_type(8))) short bf16x8;
typedef __attribute__((ext_vector_type(4))) float f32x4;
typedef __attribute__((ext_vector_type(2))) __fp16 h2;
typedef __attribute__((ext_vector_type(4))) ushort u16x4;

__device__ __forceinline__ ushort f2bf(float f) {
    unsigned u = __float_as_uint(f);
    u += 0x7FFFu + ((u >> 16) & 1u);
    return (ushort)(u >> 16);
}

// ---------------------------------------------------------------------------
// Kernel 1: per-permutation inner embed -> vec (PP x VLD, bf16)
// [frozen r23: packed-f16 pair sorting, 63.3 us, VALU-bound]
// ---------------------------------------------------------------------------
__global__ __launch_bounds__(1024, 2) void k_inner(
    const float* __restrict__ M,      // 3 x 30
    const float* __restrict__ Ws_in,  // 181 x 3
    const float* __restrict__ Wd_in,  // 181 x 27
    const float* __restrict__ Wout,   // 181 x 190
    ushort* __restrict__ Abf,         // 192 x 192 bf16 out
    ushort* __restrict__ vec)         // PP x VLD (bf16)
{
    __shared__ float Gs[NPTS * 32];
    __shared__ float WsS[192 * 3];
    __shared__ float WdS[192 * 28];

    const int tid = threadIdx.x;

    {
        int gid = blockIdx.x * 1024 + tid;
        if (gid < 192 * 192) {
            int k = gid / 192, d = gid - k * 192;
            Abf[gid] = (k < KK && d < DEMB) ? f2bf(Wout[k * DEMB + d]) : (ushort)0;
        }
    }

    for (int i = tid; i < 192 * 3; i += 1024) WsS[i] = (i < KK * 3) ? Ws_in[i] : 0.f;
    for (int i = tid; i < 192 * 28; i += 1024) {
        int k = i / 28, m = i - k * 28;
        WdS[i] = (k < KK && m < 27) ? Wd_in[k * 27 + m] : 0.f;
    }
    for (int e = tid; e < NPTS * 32; e += 1024) {
        int a = e >> 5, b = e & 31;
        Gs[e] = (b < NPTS)
            ? (M[a] * M[b] + M[NPTS + a] * M[NPTS + b] + M[2 * NPTS + a] * M[2 * NPTS + b])
            : 0.f;
    }
    __syncthreads();

    const int wave = tid >> 6;
    const int lane = tid & 63;
    const int wid = blockIdx.x * 16 + wave;   // 0..8191
    const int chunk = wid % 3;
    const int pstream = wid / 3;              // 0..2730
    const int nstream = (chunk == 2) ? 2730 : 2731;
    const int k = chunk * 64 + lane;

    const float INF = __builtin_inff();
    const bool kvalid = (k < KK);
    const float w0 = WsS[k * 3 + 0];
    const float w1 = WsS[k * 3 + 1];
    const float w2 = WsS[k * 3 + 2];
    const float* wd = WdS + k * 28;

    const int NPAIR = PP / 2;   // 12180

    for (int t = pstream; t < NPAIR; t += nstream) {
        const int p0 = 2 * t;
        int i0 = p0 / 812;            // 812 = 29*28
        int r  = p0 - i0 * 812;
        int i1 = r / 28;
        int i2 = r - i1 * 28;
        int c0 = i0;
        int c1 = i1 + (i1 >= c0 ? 1 : 0);
        int lo = min(c0, c1), hi = max(c0, c1);
        int c2a = i2;
        if (c2a >= lo) c2a++;
        if (c2a >= hi) c2a++;
        int c2b = i2 + 1;
        if (c2b >= lo) c2b++;
        if (c2b >= hi) c2b++;

        ushort* vrow0 = vec + (long)p0 * VLD;
        ushort* vrow1 = vrow0 + VLD;

        if (chunk == 0 && lane < 9) {
            int i = lane / 3, j = lane % 3;
            int cia = (i == 0) ? c0 : ((i == 1) ? c1 : c2a);
            int cja = (j == 0) ? c0 : ((j == 1) ? c1 : c2a);
            vrow0[lane] = f2bf(Gs[(cia << 5) + cja]);
            int cib = (i == 0) ? c0 : ((i == 1) ? c1 : c2b);
            int cjb = (j == 0) ? c0 : ((j == 1) ? c1 : c2b);
            vrow1[lane] = f2bf(Gs[(cib << 5) + cjb]);
        }

        const float* g0 = Gs + (c0 << 5);
        const float* g1 = Gs + (c1 << 5);
        const float* ga = Gs + (c2a << 5);
        const float* gb = Gs + (c2b << 5);
        const unsigned basem = (1u << c0) | (1u << c1);
        const unsigned maska = basem | (1u << c2a);
        const unsigned maskb = basem | (1u << c2b);

        h2 s[30];
#pragma unroll
        for (int q = 0; q < 8; ++q) {
            float4 x0 = *(const float4*)&g0[q * 4];
            float4 x1 = *(const float4*)&g1[q * 4];
            float4 xa = *(const float4*)&ga[q * 4];
            float4 xb = *(const float4*)&gb[q * 4];
            int j0 = q * 4;
            if (j0 + 0 < NPTS) {
                float c = w0 * x0.x + w1 * x1.x;
                float va = w2 * xa.x + c;
                float vb = w2 * xb.x + c;
                va = ((maska >> (j0 + 0)) & 1u) ? INF : va;
                vb = ((maskb >> (j0 + 0)) & 1u) ? INF : vb;
                s[j0 + 0] = __builtin_amdgcn_cvt_pkrtz(va, vb);
            }
            if (j0 + 1 < NPTS) {
                float c = w0 * x0.y + w1 * x1.y;
                float va = w2 * xa.y + c;
                float vb = w2 * xb.y + c;
                va = ((maska >> (j0 + 1)) & 1u) ? INF : va;
                vb = ((maskb >> (j0 + 1)) & 1u) ? INF : vb;
                s[j0 + 1] = __builtin_amdgcn_cvt_pkrtz(va, vb);
            }
            if (j0 + 2 < NPTS) {
                float c = w0 * x0.z + w1 * x1.z;
                float va = w2 * xa.z + c;
                float vb = w2 * xb.z + c;
                va = ((maska >> (j0 + 2)) & 1u) ? INF : va;
                vb = ((maskb >> (j0 + 2)) & 1u) ? INF : vb;
                s[j0 + 2] = __builtin_amdgcn_cvt_pkrtz(va, vb);
            }
            if (j0 + 3 < NPTS) {
                float c = w0 * x0.w + w1 * x1.w;
                float va = w2 * xa.w + c;
                float vb = w2 * xb.w + c;
                va = ((maska >> (j0 + 3)) & 1u) ? INF : va;
                vb = ((maskb >> (j0 + 3)) & 1u) ? INF : vb;
                s[j0 + 3] = __builtin_amdgcn_cvt_pkrtz(va, vb);
            }
        }

        // Batcher odd-even mergesort, pruned, packed pairs
#pragma unroll
        for (int pw = 1; pw < 32; pw <<= 1) {
#pragma unroll
            for (int kk = pw; kk >= 1; kk >>= 1) {
#pragma unroll
                for (int j = kk % pw; j + kk < 32; j += 2 * kk) {
#pragma unroll
                    for (int i = 0; i < kk; ++i) {
                        int a = i + j, b = i + j + kk;
                        if (a / (pw * 2) == b / (pw * 2) && b < 30
                            && !(pw == 16 && a == 27)) {
                            h2 x = s[a], y = s[b];
                            s[a] = __builtin_elementwise_min(x, y);
                            s[b] = __builtin_elementwise_max(x, y);
                        }
                    }
                }
            }
        }

        if (kvalid) {
            float emb0 = 0.f, emb1 = 0.f;
#pragma unroll
            for (int j = 0; j < 24; j += 4) {
                float4 w4 = *(const float4*)&wd[j];
                emb0 += w4.x * (float)s[j + 0].x + w4.y * (float)s[j + 1].x
                      + w4.z * (float)s[j + 2].x + w4.w * (float)s[j + 3].x;
                emb1 += w4.x * (float)s[j + 0].y + w4.y * (float)s[j + 1].y
                      + w4.z * (float)s[j + 2].y + w4.w * (float)s[j + 3].y;
            }
            {
                float4 w4 = *(const float4*)&wd[24];
                emb0 += w4.x * (float)s[24].x + w4.y * (float)s[25].x
                      + w4.z * (float)s[26].x;
                emb1 += w4.x * (float)s[24].y + w4.y * (float)s[25].y
                      + w4.z * (float)s[26].y;
            }
            vrow0[9 + k] = f2bf(emb0);
            vrow1[9 + k] = f2bf(emb1);
        } else if (k < 183) {
            vrow0[9 + k] = 0;
            vrow1[9 + k] = 0;
        }
    }
}

// ---------------------------------------------------------------------------
// Kernel 2 [r24, out-zeroing removed]: sm2TP[k][p] via bf16 MFMA.
// LDS-staged vec tile (400B-padded rows), swapped MFMA operands so D's reg
// axis is p -> one packed 8B ushort4 store per lane per kg.
// ---------------------------------------------------------------------------
__global__ __launch_bounds__(256) void k_gemm(
    const ushort* __restrict__ vecB,  // PP x 192 bf16
    const ushort* __restrict__ Abf,   // 192 x 192 bf16
    ushort* __restrict__ sm2TP)       // 181 x SNP u16 encoded keys
{
    __shared__ ushort vs[64 * 200];   // 400B-padded rows, 25.6 KB

    const int tid  = threadIdx.x;
    const int bid  = blockIdx.x;
    const int tile = bid >> 2;        // p-tile (64 p's)
    const int qtr  = bid & 3;         // kt quarter: 3 kt each
    const int wave = tid >> 6;
    const int lane = tid & 63;
    const int n = lane & 15;
    const int quad = lane >> 4;

    {
        const char* src = (const char*)(vecB + (size_t)tile * 64 * VLD);
#pragma unroll
        for (int it = 0; it < 6; ++it) {
            int byte = (it * 256 + tid) * 16;
            int row = byte / 384;
            int col = byte - row * 384;
            bf16x8 d = *(const bf16x8*)(src + byte);
            *(bf16x8*)((char*)vs + row * 400 + col) = d;
        }
    }
    __syncthreads();

    bf16x8 afrag[6];
    {
        const char* base = (const char*)vs + (wave * 16 + n) * 400;
#pragma unroll
        for (int kc = 0; kc < 6; ++kc)
            afrag[kc] = *(const bf16x8*)(base + kc * 64 + quad * 16);
    }

    const int pb = tile * 64 + wave * 16 + quad * 4;  // lane's 4 consecutive p

#pragma unroll
    for (int i = 0; i < 3; ++i) {
        const int kt = qtr * 3 + i;
        const int kg = kt * 16 + n;
        f32x4 acc = {0.f, 0.f, 0.f, 0.f};
        const ushort* arow = Abf + kg * 192;
#pragma unroll
        for (int kc = 0; kc < 6; ++kc) {
            bf16x8 bfrag = *(const bf16x8*)&arow[kc * 32 + quad * 8];
            acc = __builtin_amdgcn_mfma_f32_16x16x32_bf16(afrag[kc], bfrag, acc, 0, 0, 0);
        }
        if (kg < KK) {
            u16x4 st;
#pragma unroll
            for (int r = 0; r < 4; ++r) {
                int p = pb + r;
                unsigned e;
                if (p < PP) {
                    unsigned u = __float_as_uint(acc[r]);
                    u = (u & 0x80000000u) ? ~u : (u | 0x80000000u);
                    e = (u + 0x8000u) >> 16;     // RTN 16-bit monotone key
                } else {
                    e = 0xFFFFu;                 // pad sorts strictly last
                }
                st[r] = (ushort)e;
            }
            *(u16x4*)&sm2TP[(size_t)kg * SNP + pb] = st;  // 8B aligned
        }
    }
}

// ---------------------------------------------------------------------------
// Kernel 3 (r25): full-key-space histogram rank. One block per k. 65536 bins
// packed 2 x u16 per u32 -> hist[32768] = exactly 128 KiB LDS (max count
// 24576 < 2^15, so no cross-half carry; CDF bases also fit 15 bits).
// Phase 1: packed LDS histogram of the 24576 keys.
// Phase 2: block exclusive scan; CDF bases written back into the same packed
//          words (scan scratch reuses hist[0..15], whose owner holds its
//          words in registers across the barrier).
// Phase 3: per-ELEMENT rank: r = atomicAdd(bin)>>half (equal keys share the
//          decoded value so any intra-run assignment is exact); acc +=
//          wrow[r] * val. 24 independent gathers/thread -> ILP hides L2
//          latency; balanced by key position, not bin position (this was
//          r24-hist's 550us failure: serial per-bin wrow walk on the 1-2
//          waves owning the distribution bulk).
// Pads (0xFFFF) rank >= PP -> skipped. Result identical to r19 radix sort.
// ---------------------------------------------------------------------------
__global__ __launch_bounds__(1024, 1) void k_hist(
    const ushort* __restrict__ sm2TP,    // 181 x SNP u16 keys (padded)
    const float* __restrict__ WdOut,     // 181 x PP
    float* __restrict__ out)             // 181
{
    __shared__ unsigned hist[32768];     // exactly 128 KiB

    const int tid  = threadIdx.x;
    const int wave = tid >> 6;
    const int lane = tid & 63;
    const int k    = blockIdx.x;

    const ushort* rowU = sm2TP + (size_t)k * SNP;
    const float* wrow  = WdOut + (size_t)k * PP;

    for (int i = tid; i < 32768; i += 1024) hist[i] = 0u;
    __syncthreads();

    // ---- phase 1: packed histogram ----
    unsigned keys[24];
#pragma unroll
    for (int j = 0; j < 24; ++j) {
        unsigned u = rowU[tid + j * 1024];
        keys[j] = u;
        atomicAdd(&hist[u >> 1], 1u << ((u & 1u) << 4));
    }
    __syncthreads();

    // ---- phase 2: exclusive scan over 65536 bins ----
    // thread t owns words [32t, 32t+32) = bins [64t, 64t+64)
    unsigned w[32];
#pragma unroll
    for (int i = 0; i < 32; ++i) w[i] = hist[tid * 32 + i];
    unsigned tsum = 0;
#pragma unroll
    for (int i = 0; i < 32; ++i)
        tsum += (w[i] & 0xFFFFu) + (w[i] >> 16);

    // wave inclusive scan of tsum
    unsigned inc = tsum;
#pragma unroll
    for (int off = 1; off < 64; off <<= 1) {
        unsigned o = (unsigned)__shfl_up((int)inc, off, 64);
        if (lane >= off) inc += o;
    }
    __syncthreads();                       // everyone captured w[] in regs
    if (lane == 63) hist[wave] = inc;      // wave totals -> scratch
    __syncthreads();
    unsigned wbase = 0;
#pragma unroll
    for (int ww = 0; ww < 16; ++ww)
        wbase += (ww < wave) ? hist[ww] : 0u;   // broadcast reads
    __syncthreads();                       // reads done before CDF writeback

    unsigned running = wbase + (inc - tsum);
#pragma unroll
    for (int i = 0; i < 32; ++i) {
        unsigned lob = running;            // base of bin 2*(32t+i)
        running += (w[i] & 0xFFFFu);
        unsigned hib = running;            // base of bin 2*(32t+i)+1
        running += (w[i] >> 16);
        hist[tid * 32 + i] = lob | (hib << 16);
    }
    __syncthreads();

    // ---- phase 3: per-element rank + fused dot ----
    float acc = 0.f;
#pragma unroll
    for (int j = 0; j < 24; ++j) {
        unsigned u = keys[j];
        unsigned sh = (u & 1u) << 4;
        unsigned old = atomicAdd(&hist[u >> 1], 1u << sh);
        unsigned r = (old >> sh) & 0xFFFFu;
        if (r < (unsigned)PP) {
            unsigned raw16 = (u & 0x8000u) ? (u & 0x7FFFu) : ((~u) & 0xFFFFu);
            acc += wrow[r] * __uint_as_float(raw16 << 16);
        }
    }

#pragma unroll
    for (int off = 32; off > 0; off >>= 1)
        acc += __shfl_down(acc, off, 64);
    __syncthreads();                       // hist no longer needed as CDF
    if (lane == 0) ((float*)hist)[wave] = acc;
    __syncthreads();
    if (tid == 0) {
        float t = 0.f;
#pragma unroll
        for (int ww = 0; ww < 16; ++ww) t += ((float*)hist)[ww];
        out[k] = t;
    }
}

// ---------------------------------------------------------------------------
extern "C" void kernel_launch(void* const* d_in, const int* in_sizes, int n_in,
                              void* d_out, int out_size, void* d_ws, size_t ws_size,
                              hipStream_t stream) {
    const float* M      = (const float*)d_in[0];
    const float* Ws_in  = (const float*)d_in[1];
    const float* Wd_in  = (const float*)d_in[2];
    const float* Ws_out = (const float*)d_in[3];
    const float* Wd_out = (const float*)d_in[4];
    float* out = (float*)d_out;

    // workspace layout (18.4 MB):
    // [0, 9.36 MB):    vecB (PP x 192 bf16)
    // [9.36, 18.26):   sm2TP (181 x SNP u16 keys)
    // [18.26, +74KB):  Abf (192 x 192 bf16)
    char* ws = (char*)d_ws;
    ushort* vecB  = (ushort*)ws;
    ushort* sm2TP = (ushort*)(ws + (size_t)PP * VLD * 2);
    ushort* Abf   = (ushort*)(ws + (size_t)PP * VLD * 2 + (size_t)KK * SNP * 2);

    k_inner<<<512, 1024, 0, stream>>>(M, Ws_in, Wd_in, Ws_out, Abf, vecB);

    k_gemm<<<(SNP / 64) * 4, 256, 0, stream>>>(vecB, Abf, sm2TP);

    k_hist<<<KK, 1024, 0, stream>>>(sm2TP, Wd_out, out);
}

// Round 5
// 185.811 us; speedup vs baseline: 3.6415x; 1.0859x over previous
//
#include <hip/hip_runtime.h>
#include <hip/hip_bf16.h>

#define DIMK 3
#define NPTS 30
#define KK   181
#define PP   24360
#define DEMB 190
#define VLD  192   // padded vec row stride (bf16 elements)
#define SNP  24576 // padded row length = 16*1536 (sort rows AND sm2T stride)

typedef __attribute__((ext_vector_type(8))) short bf16x8;
typedef __attribute__((ext_vector_type(4))) float f32x4;
typedef __attribute__((ext_vector_type(2))) __fp16 h2;
typedef __attribute__((ext_vector_type(4))) ushort u16x4;
typedef __attribute__((ext_vector_type(4))) unsigned u32x4;

__device__ __forceinline__ ushort f2bf(float f) {
    unsigned u = __float_as_uint(f);
    u += 0x7FFFu + ((u >> 16) & 1u);
    return (ushort)(u >> 16);
}

// ---------------------------------------------------------------------------
// Kernel 1 (r26): packed-f16 pair sorting [r23] + WAVE-UNIFORM SCALARIZATION.
// t and everything derived from it (decode divisions, c0/c1/c2a/c2b, INF
// masks, Gs row addresses, vrow bases) is identical across the 64 lanes of a
// wave, but the compiler cannot prove tid>>6 uniform. readfirstlane(wave)
// forces the whole chain onto the SALU pipe: decode becomes s_mul_hi magic
// division, mask bit-tests become s_lshr/s_and, and each INF select drops to
// one v_cndmask with an SGPR-pair condition (was ~3-4 VALU each, x60/task).
// ---------------------------------------------------------------------------
__global__ __launch_bounds__(1024, 2) void k_inner(
    const float* __restrict__ M,      // 3 x 30
    const float* __restrict__ Ws_in,  // 181 x 3
    const float* __restrict__ Wd_in,  // 181 x 27
    const float* __restrict__ Wout,   // 181 x 190
    ushort* __restrict__ Abf,         // 192 x 192 bf16 out
    ushort* __restrict__ vec)         // PP x VLD (bf16)
{
    __shared__ float Gs[NPTS * 32];
    __shared__ float WsS[192 * 3];
    __shared__ float WdS[192 * 28];

    const int tid = threadIdx.x;

    {
        int gid = blockIdx.x * 1024 + tid;
        if (gid < 192 * 192) {
            int k = gid / 192, d = gid - k * 192;
            Abf[gid] = (k < KK && d < DEMB) ? f2bf(Wout[k * DEMB + d]) : (ushort)0;
        }
    }

    for (int i = tid; i < 192 * 3; i += 1024) WsS[i] = (i < KK * 3) ? Ws_in[i] : 0.f;
    for (int i = tid; i < 192 * 28; i += 1024) {
        int k = i / 28, m = i - k * 28;
        WdS[i] = (k < KK && m < 27) ? Wd_in[k * 27 + m] : 0.f;
    }
    for (int e = tid; e < NPTS * 32; e += 1024) {
        int a = e >> 5, b = e & 31;
        Gs[e] = (b < NPTS)
            ? (M[a] * M[b] + M[NPTS + a] * M[NPTS + b] + M[2 * NPTS + a] * M[2 * NPTS + b])
            : 0.f;
    }
    __syncthreads();

    const int wave = __builtin_amdgcn_readfirstlane(tid >> 6);  // wave-uniform
    const int lane = tid & 63;
    const int wid = blockIdx.x * 16 + wave;   // 0..8191, uniform
    const int chunk = wid % 3;
    const int pstream = wid / 3;              // 0..2730
    const int nstream = (chunk == 2) ? 2730 : 2731;
    const int k = chunk * 64 + lane;

    const float INF = __builtin_inff();
    const bool kvalid = (k < KK);
    const float w0 = WsS[k * 3 + 0];
    const float w1 = WsS[k * 3 + 1];
    const float w2 = WsS[k * 3 + 2];
    const float* wd = WdS + k * 28;

    const int NPAIR = PP / 2;   // 12180

    for (int t = pstream; t < NPAIR; t += nstream) {
        const int p0 = 2 * t;                 // uniform
        int i0 = p0 / 812;                    // 812 = 29*28  (scalar magic-div)
        int r  = p0 - i0 * 812;
        int i1 = r / 28;
        int i2 = r - i1 * 28;
        int c0 = i0;
        int c1 = i1 + (i1 >= c0 ? 1 : 0);
        int lo = min(c0, c1), hi = max(c0, c1);
        int c2a = i2;
        if (c2a >= lo) c2a++;
        if (c2a >= hi) c2a++;
        int c2b = i2 + 1;
        if (c2b >= lo) c2b++;
        if (c2b >= hi) c2b++;

        ushort* vrow0 = vec + (long)p0 * VLD;
        ushort* vrow1 = vrow0 + VLD;

        if (chunk == 0 && lane < 9) {
            int i = lane / 3, j = lane % 3;
            int cia = (i == 0) ? c0 : ((i == 1) ? c1 : c2a);
            int cja = (j == 0) ? c0 : ((j == 1) ? c1 : c2a);
            vrow0[lane] = f2bf(Gs[(cia << 5) + cja]);
            int cib = (i == 0) ? c0 : ((i == 1) ? c1 : c2b);
            int cjb = (j == 0) ? c0 : ((j == 1) ? c1 : c2b);
            vrow1[lane] = f2bf(Gs[(cib << 5) + cjb]);
        }

        const float* g0 = Gs + (c0 << 5);
        const float* g1 = Gs + (c1 << 5);
        const float* ga = Gs + (c2a << 5);
        const float* gb = Gs + (c2b << 5);
        const unsigned basem = (1u << c0) | (1u << c1);   // uniform
        const unsigned maska = basem | (1u << c2a);       // uniform
        const unsigned maskb = basem | (1u << c2b);       // uniform

        h2 s[30];
#pragma unroll
        for (int q = 0; q < 8; ++q) {
            float4 x0 = *(const float4*)&g0[q * 4];
            float4 x1 = *(const float4*)&g1[q * 4];
            float4 xa = *(const float4*)&ga[q * 4];
            float4 xb = *(const float4*)&gb[q * 4];
            int j0 = q * 4;
            if (j0 + 0 < NPTS) {
                float c = w0 * x0.x + w1 * x1.x;
                float va = w2 * xa.x + c;
                float vb = w2 * xb.x + c;
                va = ((maska >> (j0 + 0)) & 1u) ? INF : va;
                vb = ((maskb >> (j0 + 0)) & 1u) ? INF : vb;
                s[j0 + 0] = __builtin_amdgcn_cvt_pkrtz(va, vb);
            }
            if (j0 + 1 < NPTS) {
                float c = w0 * x0.y + w1 * x1.y;
                float va = w2 * xa.y + c;
                float vb = w2 * xb.y + c;
                va = ((maska >> (j0 + 1)) & 1u) ? INF : va;
                vb = ((maskb >> (j0 + 1)) & 1u) ? INF : vb;
                s[j0 + 1] = __builtin_amdgcn_cvt_pkrtz(va, vb);
            }
            if (j0 + 2 < NPTS) {
                float c = w0 * x0.z + w1 * x1.z;
                float va = w2 * xa.z + c;
                float vb = w2 * xb.z + c;
                va = ((maska >> (j0 + 2)) & 1u) ? INF : va;
                vb = ((maskb >> (j0 + 2)) & 1u) ? INF : vb;
                s[j0 + 2] = __builtin_amdgcn_cvt_pkrtz(va, vb);
            }
            if (j0 + 3 < NPTS) {
                float c = w0 * x0.w + w1 * x1.w;
                float va = w2 * xa.w + c;
                float vb = w2 * xb.w + c;
                va = ((maska >> (j0 + 3)) & 1u) ? INF : va;
                vb = ((maskb >> (j0 + 3)) & 1u) ? INF : vb;
                s[j0 + 3] = __builtin_amdgcn_cvt_pkrtz(va, vb);
            }
        }

        // Batcher odd-even mergesort, pruned, packed pairs
#pragma unroll
        for (int pw = 1; pw < 32; pw <<= 1) {
#pragma unroll
            for (int kk = pw; kk >= 1; kk >>= 1) {
#pragma unroll
                for (int j = kk % pw; j + kk < 32; j += 2 * kk) {
#pragma unroll
                    for (int i = 0; i < kk; ++i) {
                        int a = i + j, b = i + j + kk;
                        if (a / (pw * 2) == b / (pw * 2) && b < 30
                            && !(pw == 16 && a == 27)) {
                            h2 x = s[a], y = s[b];
                            s[a] = __builtin_elementwise_min(x, y);
                            s[b] = __builtin_elementwise_max(x, y);
                        }
                    }
                }
            }
        }

        if (kvalid) {
            float emb0 = 0.f, emb1 = 0.f;
#pragma unroll
            for (int j = 0; j < 24; j += 4) {
                float4 w4 = *(const float4*)&wd[j];
                emb0 += w4.x * (float)s[j + 0].x + w4.y * (float)s[j + 1].x
                      + w4.z * (float)s[j + 2].x + w4.w * (float)s[j + 3].x;
                emb1 += w4.x * (float)s[j + 0].y + w4.y * (float)s[j + 1].y
                      + w4.z * (float)s[j + 2].y + w4.w * (float)s[j + 3].y;
            }
            {
                float4 w4 = *(const float4*)&wd[24];
                emb0 += w4.x * (float)s[24].x + w4.y * (float)s[25].x
                      + w4.z * (float)s[26].x;
                emb1 += w4.x * (float)s[24].y + w4.y * (float)s[25].y
                      + w4.z * (float)s[26].y;
            }
            vrow0[9 + k] = f2bf(emb0);
            vrow1[9 + k] = f2bf(emb1);
        } else if (k < 183) {
            vrow0[9 + k] = 0;
            vrow1[9 + k] = 0;
        }
    }
}

// ---------------------------------------------------------------------------
// Kernel 2 (r26): quarters MERGED — one block does all 12 kt for its p-tile
// (grid 384, was 1536). Cuts vecB L2 re-reads 4x and staging barriers 4x.
// Also zeroes out[] for k_hist's cross-block atomics.
// ---------------------------------------------------------------------------
__global__ __launch_bounds__(256) void k_gemm(
    const ushort* __restrict__ vecB,  // PP x 192 bf16
    const ushort* __restrict__ Abf,   // 192 x 192 bf16
    ushort* __restrict__ sm2TP,       // 181 x SNP u16 encoded keys
    float* __restrict__ out)          // 181 (zeroed here)
{
    __shared__ ushort vs[64 * 200];   // 400B-padded rows, 25.6 KB

    const int tid  = threadIdx.x;
    const int tile = blockIdx.x;      // p-tile (64 p's), 0..383
    const int wave = tid >> 6;
    const int lane = tid & 63;
    const int n = lane & 15;
    const int quad = lane >> 4;

    if (tile == 0 && tid < KK) out[tid] = 0.f;

    {
        const char* src = (const char*)(vecB + (size_t)tile * 64 * VLD);
#pragma unroll
        for (int it = 0; it < 6; ++it) {
            int byte = (it * 256 + tid) * 16;
            int row = byte / 384;
            int col = byte - row * 384;
            bf16x8 d = *(const bf16x8*)(src + byte);
            *(bf16x8*)((char*)vs + row * 400 + col) = d;
        }
    }
    __syncthreads();

    bf16x8 afrag[6];
    {
        const char* base = (const char*)vs + (wave * 16 + n) * 400;
#pragma unroll
        for (int kc = 0; kc < 6; ++kc)
            afrag[kc] = *(const bf16x8*)(base + kc * 64 + quad * 16);
    }

    const int pb = tile * 64 + wave * 16 + quad * 4;  // lane's 4 consecutive p

#pragma unroll 3
    for (int kt = 0; kt < 12; ++kt) {
        const int kg = kt * 16 + n;
        f32x4 acc = {0.f, 0.f, 0.f, 0.f};
        const ushort* arow = Abf + kg * 192;
#pragma unroll
        for (int kc = 0; kc < 6; ++kc) {
            bf16x8 bfrag = *(const bf16x8*)&arow[kc * 32 + quad * 8];
            acc = __builtin_amdgcn_mfma_f32_16x16x32_bf16(afrag[kc], bfrag, acc, 0, 0, 0);
        }
        if (kg < KK) {
            u16x4 st;
#pragma unroll
            for (int r = 0; r < 4; ++r) {
                int p = pb + r;
                unsigned e;
                if (p < PP) {
                    unsigned u = __float_as_uint(acc[r]);
                    u = (u & 0x80000000u) ? ~u : (u | 0x80000000u);
                    e = (u + 0x8000u) >> 16;     // RTN 16-bit monotone key
                } else {
                    e = 0xFFFFu;                 // pad sorts strictly last
                }
                st[r] = (ushort)e;
            }
            *(u16x4*)&sm2TP[(size_t)kg * SNP + pb] = st;  // 8B aligned
        }
    }
}

// ---------------------------------------------------------------------------
// Kernel 3 (r26): histogram rank, 2-WAY KEY-SPACE SPLIT. Counts fit u16
// (max 24576), so each half-space needs hist[16384] u32 = 64 KiB -> 2 blocks
// per CU (was 1 at 128 KiB), grid 362, 32 waves/CU. Each block histograms +
// ranks only keys in its 32768-bin half; keys below its base are counted for
// the rank offset. Per-element rank via packed LDS atomicAdd (equal keys
// share the decoded value -> any intra-run assignment exact). Partial dots
// merged with one atomicAdd per block into out[k] (zeroed in k_gemm).
// ---------------------------------------------------------------------------
__global__ __launch_bounds__(1024, 2) void k_hist(
    const ushort* __restrict__ sm2TP,    // 181 x SNP u16 keys (padded)
    const float* __restrict__ WdOut,     // 181 x PP
    float* __restrict__ out)             // 181 (accumulated)
{
    __shared__ unsigned hist[16384];     // 64 KiB: u16-packed counts, 32768 bins
    __shared__ unsigned wred[16];
    __shared__ float fred[16];

    const int tid  = threadIdx.x;
    const int wave = tid >> 6;
    const int lane = tid & 63;
    const int k = blockIdx.x >> 1;
    const int q = blockIdx.x & 1;
    const unsigned base = (unsigned)q << 15;

    const ushort* rowU = sm2TP + (size_t)k * SNP;
    const float* wrow  = WdOut + (size_t)k * PP;

    for (int i = tid; i < 4096; i += 1024)
        ((u32x4*)hist)[i] = (u32x4){0u, 0u, 0u, 0u};
    __syncthreads();

    // ---- phase 1: packed histogram of this half + below-count ----
    unsigned keys[24];
    unsigned below = 0;
#pragma unroll
    for (int j = 0; j < 24; ++j) {
        unsigned u = rowU[tid + j * 1024];
        keys[j] = u;
        unsigned rel = u - base;
        if (rel < 32768u)
            atomicAdd(&hist[rel >> 1], 1u << ((rel & 1u) << 4));
        else
            below += (u < base) ? 1u : 0u;
    }
    {
        unsigned b = below;
#pragma unroll
        for (int off = 32; off > 0; off >>= 1)
            b += (unsigned)__shfl_down((int)b, off, 64);
        if (lane == 0) wred[wave] = b;
    }
    __syncthreads();   // hist + wred complete

    unsigned below_tot = 0;
#pragma unroll
    for (int ww = 0; ww < 16; ++ww) below_tot += wred[ww];

    // ---- phase 2: exclusive scan; thread t owns words [16t,16t+16) ----
    unsigned w[16];
#pragma unroll
    for (int i = 0; i < 16; ++i) w[i] = hist[tid * 16 + i];
    unsigned tsum = 0;
#pragma unroll
    for (int i = 0; i < 16; ++i)
        tsum += (w[i] & 0xFFFFu) + (w[i] >> 16);

    unsigned inc = tsum;
#pragma unroll
    for (int off = 1; off < 64; off <<= 1) {
        unsigned o = (unsigned)__shfl_up((int)inc, off, 64);
        if (lane >= off) inc += o;
    }
    __syncthreads();                     // all hist/wred reads done
    if (lane == 63) wred[wave] = inc;    // wave totals
    __syncthreads();
    unsigned wbase = 0;
#pragma unroll
    for (int ww = 0; ww < 16; ++ww)
        wbase += (ww < wave) ? wred[ww] : 0u;

    unsigned running = below_tot + wbase + (inc - tsum);
#pragma unroll
    for (int i = 0; i < 16; ++i) {
        unsigned lob = running;
        running += (w[i] & 0xFFFFu);
        unsigned hib = running;
        running += (w[i] >> 16);
        hist[tid * 16 + i] = lob | (hib << 16);
    }
    __syncthreads();

    // ---- phase 3: per-element rank + fused dot (this half only) ----
    float acc = 0.f;
#pragma unroll
    for (int j = 0; j < 24; ++j) {
        unsigned u = keys[j];
        unsigned rel = u - base;
        if (rel < 32768u) {
            unsigned sh = (rel & 1u) << 4;
            unsigned old = atomicAdd(&hist[rel >> 1], 1u << sh);
            unsigned r = (old >> sh) & 0xFFFFu;
            if (r < (unsigned)PP) {
                unsigned raw16 = (u & 0x8000u) ? (u & 0x7FFFu) : ((~u) & 0xFFFFu);
                acc += wrow[r] * __uint_as_float(raw16 << 16);
            }
        }
    }

#pragma unroll
    for (int off = 32; off > 0; off >>= 1)
        acc += __shfl_down(acc, off, 64);
    if (lane == 0) fred[wave] = acc;
    __syncthreads();
    if (tid == 0) {
        float t = 0.f;
#pragma unroll
        for (int ww = 0; ww < 16; ++ww) t += fred[ww];
        atomicAdd(&out[k], t);
    }
}

// ---------------------------------------------------------------------------
extern "C" void kernel_launch(void* const* d_in, const int* in_sizes, int n_in,
                              void* d_out, int out_size, void* d_ws, size_t ws_size,
                              hipStream_t stream) {
    const float* M      = (const float*)d_in[0];
    const float* Ws_in  = (const float*)d_in[1];
    const float* Wd_in  = (const float*)d_in[2];
    const float* Ws_out = (const float*)d_in[3];
    const float* Wd_out = (const float*)d_in[4];
    float* out = (float*)d_out;

    // workspace layout (18.4 MB):
    // [0, 9.36 MB):    vecB (PP x 192 bf16)
    // [9.36, 18.26):   sm2TP (181 x SNP u16 keys)
    // [18.26, +74KB):  Abf (192 x 192 bf16)
    char* ws = (char*)d_ws;
    ushort* vecB  = (ushort*)ws;
    ushort* sm2TP = (ushort*)(ws + (size_t)PP * VLD * 2);
    ushort* Abf   = (ushort*)(ws + (size_t)PP * VLD * 2 + (size_t)KK * SNP * 2);

    k_inner<<<512, 1024, 0, stream>>>(M, Ws_in, Wd_in, Ws_out, Abf, vecB);

    k_gemm<<<SNP / 64, 256, 0, stream>>>(vecB, Abf, sm2TP, out);

    k_hist<<<KK * 2, 1024, 0, stream>>>(sm2TP, Wd_out, out);
}

// Round 7
// 165.420 us; speedup vs baseline: 4.0904x; 1.1233x over previous
//
#include <hip/hip_runtime.h>
#include <hip/hip_bf16.h>

#define DIMK 3
#define NPTS 30
#define KK   181
#define PP   24360
#define DEMB 190
#define VLD  192   // padded vec row stride (bf16 elements)
#define SNP  24576 // padded row length = 16*1536 (sort rows AND sm2T stride)

typedef __attribute__((ext_vector_type(8))) short bf16x8;
typedef __attribute__((ext_vector_type(4))) float f32x4;
typedef __attribute__((ext_vector_type(2))) __fp16 h2;
typedef __attribute__((ext_vector_type(4))) ushort u16x4;

__device__ __forceinline__ ushort f2bf(float f) {
    unsigned u = __float_as_uint(f);
    u += 0x7FFFu + ((u >> 16) & 1u);
    return (ushort)(u >> 16);
}

// ---------------------------------------------------------------------------
// Kernel 1 [frozen r26]: packed-f16 pair sorting + wave-uniform scalarization.
// 54.8 us, VALU-bound.
// ---------------------------------------------------------------------------
__global__ __launch_bounds__(1024, 2) void k_inner(
    const float* __restrict__ M,      // 3 x 30
    const float* __restrict__ Ws_in,  // 181 x 3
    const float* __restrict__ Wd_in,  // 181 x 27
    const float* __restrict__ Wout,   // 181 x 190
    ushort* __restrict__ Abf,         // 192 x 192 bf16 out
    ushort* __restrict__ vec)         // PP x VLD (bf16)
{
    __shared__ float Gs[NPTS * 32];
    __shared__ float WsS[192 * 3];
    __shared__ float WdS[192 * 28];

    const int tid = threadIdx.x;

    {
        int gid = blockIdx.x * 1024 + tid;
        if (gid < 192 * 192) {
            int k = gid / 192, d = gid - k * 192;
            Abf[gid] = (k < KK && d < DEMB) ? f2bf(Wout[k * DEMB + d]) : (ushort)0;
        }
    }

    for (int i = tid; i < 192 * 3; i += 1024) WsS[i] = (i < KK * 3) ? Ws_in[i] : 0.f;
    for (int i = tid; i < 192 * 28; i += 1024) {
        int k = i / 28, m = i - k * 28;
        WdS[i] = (k < KK && m < 27) ? Wd_in[k * 27 + m] : 0.f;
    }
    for (int e = tid; e < NPTS * 32; e += 1024) {
        int a = e >> 5, b = e & 31;
        Gs[e] = (b < NPTS)
            ? (M[a] * M[b] + M[NPTS + a] * M[NPTS + b] + M[2 * NPTS + a] * M[2 * NPTS + b])
            : 0.f;
    }
    __syncthreads();

    const int wave = __builtin_amdgcn_readfirstlane(tid >> 6);  // wave-uniform
    const int lane = tid & 63;
    const int wid = blockIdx.x * 16 + wave;   // 0..8191, uniform
    const int chunk = wid % 3;
    const int pstream = wid / 3;              // 0..2730
    const int nstream = (chunk == 2) ? 2730 : 2731;
    const int k = chunk * 64 + lane;

    const float INF = __builtin_inff();
    const bool kvalid = (k < KK);
    const float w0 = WsS[k * 3 + 0];
    const float w1 = WsS[k * 3 + 1];
    const float w2 = WsS[k * 3 + 2];
    const float* wd = WdS + k * 28;

    const int NPAIR = PP / 2;   // 12180

    for (int t = pstream; t < NPAIR; t += nstream) {
        const int p0 = 2 * t;                 // uniform
        int i0 = p0 / 812;                    // 812 = 29*28  (scalar magic-div)
        int r  = p0 - i0 * 812;
        int i1 = r / 28;
        int i2 = r - i1 * 28;
        int c0 = i0;
        int c1 = i1 + (i1 >= c0 ? 1 : 0);
        int lo = min(c0, c1), hi = max(c0, c1);
        int c2a = i2;
        if (c2a >= lo) c2a++;
        if (c2a >= hi) c2a++;
        int c2b = i2 + 1;
        if (c2b >= lo) c2b++;
        if (c2b >= hi) c2b++;

        ushort* vrow0 = vec + (long)p0 * VLD;
        ushort* vrow1 = vrow0 + VLD;

        if (chunk == 0 && lane < 9) {
            int i = lane / 3, j = lane % 3;
            int cia = (i == 0) ? c0 : ((i == 1) ? c1 : c2a);
            int cja = (j == 0) ? c0 : ((j == 1) ? c1 : c2a);
            vrow0[lane] = f2bf(Gs[(cia << 5) + cja]);
            int cib = (i == 0) ? c0 : ((i == 1) ? c1 : c2b);
            int cjb = (j == 0) ? c0 : ((j == 1) ? c1 : c2b);
            vrow1[lane] = f2bf(Gs[(cib << 5) + cjb]);
        }

        const float* g0 = Gs + (c0 << 5);
        const float* g1 = Gs + (c1 << 5);
        const float* ga = Gs + (c2a << 5);
        const float* gb = Gs + (c2b << 5);
        const unsigned basem = (1u << c0) | (1u << c1);   // uniform
        const unsigned maska = basem | (1u << c2a);       // uniform
        const unsigned maskb = basem | (1u << c2b);       // uniform

        h2 s[30];
#pragma unroll
        for (int q = 0; q < 8; ++q) {
            float4 x0 = *(const float4*)&g0[q * 4];
            float4 x1 = *(const float4*)&g1[q * 4];
            float4 xa = *(const float4*)&ga[q * 4];
            float4 xb = *(const float4*)&gb[q * 4];
            int j0 = q * 4;
            if (j0 + 0 < NPTS) {
                float c = w0 * x0.x + w1 * x1.x;
                float va = w2 * xa.x + c;
                float vb = w2 * xb.x + c;
                va = ((maska >> (j0 + 0)) & 1u) ? INF : va;
                vb = ((maskb >> (j0 + 0)) & 1u) ? INF : vb;
                s[j0 + 0] = __builtin_amdgcn_cvt_pkrtz(va, vb);
            }
            if (j0 + 1 < NPTS) {
                float c = w0 * x0.y + w1 * x1.y;
                float va = w2 * xa.y + c;
                float vb = w2 * xb.y + c;
                va = ((maska >> (j0 + 1)) & 1u) ? INF : va;
                vb = ((maskb >> (j0 + 1)) & 1u) ? INF : vb;
                s[j0 + 1] = __builtin_amdgcn_cvt_pkrtz(va, vb);
            }
            if (j0 + 2 < NPTS) {
                float c = w0 * x0.z + w1 * x1.z;
                float va = w2 * xa.z + c;
                float vb = w2 * xb.z + c;
                va = ((maska >> (j0 + 2)) & 1u) ? INF : va;
                vb = ((maskb >> (j0 + 2)) & 1u) ? INF : vb;
                s[j0 + 2] = __builtin_amdgcn_cvt_pkrtz(va, vb);
            }
            if (j0 + 3 < NPTS) {
                float c = w0 * x0.w + w1 * x1.w;
                float va = w2 * xa.w + c;
                float vb = w2 * xb.w + c;
                va = ((maska >> (j0 + 3)) & 1u) ? INF : va;
                vb = ((maskb >> (j0 + 3)) & 1u) ? INF : vb;
                s[j0 + 3] = __builtin_amdgcn_cvt_pkrtz(va, vb);
            }
        }

        // Batcher odd-even mergesort, pruned, packed pairs
#pragma unroll
        for (int pw = 1; pw < 32; pw <<= 1) {
#pragma unroll
            for (int kk = pw; kk >= 1; kk >>= 1) {
#pragma unroll
                for (int j = kk % pw; j + kk < 32; j += 2 * kk) {
#pragma unroll
                    for (int i = 0; i < kk; ++i) {
                        int a = i + j, b = i + j + kk;
                        if (a / (pw * 2) == b / (pw * 2) && b < 30
                            && !(pw == 16 && a == 27)) {
                            h2 x = s[a], y = s[b];
                            s[a] = __builtin_elementwise_min(x, y);
                            s[b] = __builtin_elementwise_max(x, y);
                        }
                    }
                }
            }
        }

        if (kvalid) {
            float emb0 = 0.f, emb1 = 0.f;
#pragma unroll
            for (int j = 0; j < 24; j += 4) {
                float4 w4 = *(const float4*)&wd[j];
                emb0 += w4.x * (float)s[j + 0].x + w4.y * (float)s[j + 1].x
                      + w4.z * (float)s[j + 2].x + w4.w * (float)s[j + 3].x;
                emb1 += w4.x * (float)s[j + 0].y + w4.y * (float)s[j + 1].y
                      + w4.z * (float)s[j + 2].y + w4.w * (float)s[j + 3].y;
            }
            {
                float4 w4 = *(const float4*)&wd[24];
                emb0 += w4.x * (float)s[24].x + w4.y * (float)s[25].x
                      + w4.z * (float)s[26].x;
                emb1 += w4.x * (float)s[24].y + w4.y * (float)s[25].y
                      + w4.z * (float)s[26].y;
            }
            vrow0[9 + k] = f2bf(emb0);
            vrow1[9 + k] = f2bf(emb1);
        } else if (k < 183) {
            vrow0[9 + k] = 0;
            vrow1[9 + k] = 0;
        }
    }
}

// ---------------------------------------------------------------------------
// Kernel 2 [r27]: grid 1536 (p-tile x kt-quarter, 256 thr) -> 24 waves/CU.
// Direct 16B global loads (no LDS staging; zero inter-wave reuse), swapped
// MFMA operands -> packed 8B coalesced key stores.
// ---------------------------------------------------------------------------
__global__ __launch_bounds__(256) void k_gemm(
    const ushort* __restrict__ vecB,  // PP x 192 bf16
    const ushort* __restrict__ Abf,   // 192 x 192 bf16
    ushort* __restrict__ sm2TP)       // 181 x SNP u16 encoded keys
{
    const int tid  = threadIdx.x;
    const int bid  = blockIdx.x;
    const int tile = bid >> 2;        // p-tile (64 p's)
    const int qtr  = bid & 3;         // kt quarter: 3 kt each
    const int wave = tid >> 6;
    const int lane = tid & 63;
    const int n = lane & 15;
    const int quad = lane >> 4;

    // A operand: vec row (p axis). Rows >= PP read workspace garbage -> their
    // D rows are encoded as pads below, never consumed.
    const int prow = tile * 64 + wave * 16 + n;
    bf16x8 afrag[6];
    {
        const ushort* row = vecB + (size_t)prow * VLD;
#pragma unroll
        for (int kc = 0; kc < 6; ++kc)
            afrag[kc] = *(const bf16x8*)&row[kc * 32 + quad * 8];
    }

    const int pb = tile * 64 + wave * 16 + quad * 4;  // lane's 4 consecutive p

#pragma unroll
    for (int i = 0; i < 3; ++i) {
        const int kt = qtr * 3 + i;
        const int kg = kt * 16 + n;
        f32x4 acc = {0.f, 0.f, 0.f, 0.f};
        const ushort* arow = Abf + kg * 192;
#pragma unroll
        for (int kc = 0; kc < 6; ++kc) {
            bf16x8 bfrag = *(const bf16x8*)&arow[kc * 32 + quad * 8];
            acc = __builtin_amdgcn_mfma_f32_16x16x32_bf16(afrag[kc], bfrag, acc, 0, 0, 0);
        }
        if (kg < KK) {
            u16x4 st;
#pragma unroll
            for (int r = 0; r < 4; ++r) {
                int p = pb + r;
                unsigned e;
                if (p < PP) {
                    unsigned u = __float_as_uint(acc[r]);
                    u = (u & 0x80000000u) ? ~u : (u | 0x80000000u);
                    e = (u + 0x8000u) >> 16;     // RTN 16-bit monotone key
                } else {
                    e = 0xFFFFu;                 // pad sorts strictly last
                }
                st[r] = (ushort)e;
            }
            *(u16x4*)&sm2TP[(size_t)kg * SNP + pb] = st;  // 8B aligned
        }
    }
}

// ---------------------------------------------------------------------------
// Kernel 3 (r28 = r27 + NaN fix): histogram + in-LDS prefix sum. One block
// per k. Bin b (rank-base r, count c) contributes val(b)*(PS[r+c]-PS[r]).
// r27 BUG: pad bin 0xFFFF decodes to 0x7FFF0000 = NaN; its window is
// PS[PP]-PS[PP]=0 -> NaN*0 = NaN poisoned acc. FIX: guard with r1 < r2 —
// pads (and only pads: exactly PP valid keys rank < PP) clamp to r1==r2,
// so the NaN decode is never multiplied.
// ---------------------------------------------------------------------------
__global__ __launch_bounds__(1024, 1) void k_hist(
    const ushort* __restrict__ sm2TP,    // 181 x SNP u16 keys (padded)
    const float* __restrict__ WdOut,     // 181 x PP
    float* __restrict__ out)             // 181
{
    __shared__ float PS[PP + 1];         // 97444 B
    __shared__ unsigned hist[16384];     // 65536 B (u16-packed, 32768 bins/pass)
    __shared__ unsigned wred[16];
    __shared__ float fred[16];

    const int tid  = threadIdx.x;
    const int wave = tid >> 6;
    const int lane = tid & 63;
    const int k    = blockIdx.x;

    const ushort* rowU = sm2TP + (size_t)k * SNP;
    const float* wrow  = WdOut + (size_t)k * PP;

    // ---- PS: load wrow, in-place exclusive block scan (chunk=25) ----
#pragma unroll
    for (int j = 0; j < 24; ++j) {
        int i = tid + j * 1024;
        if (i < PP) PS[i] = wrow[i];
    }
    __syncthreads();

    float v[25];
    float csum = 0.f;
    const int cbase = tid * 25;
    if (tid < 975) {
#pragma unroll
        for (int j = 0; j < 25; ++j) {
            int i = cbase + j;
            v[j] = (i < PP) ? PS[i] : 0.f;
            csum += v[j];
        }
    }
    float finc = csum;
#pragma unroll
    for (int off = 1; off < 64; off <<= 1) {
        float o = __shfl_up(finc, off, 64);
        if (lane >= off) finc += o;
    }
    __syncthreads();                   // all raw PS reads done
    if (lane == 63) fred[wave] = finc;
    __syncthreads();
    float fbase = 0.f;
#pragma unroll
    for (int ww = 0; ww < 16; ++ww) fbase += (ww < wave) ? fred[ww] : 0.f;
    if (tid < 975) {
        float run = fbase + (finc - csum);
#pragma unroll
        for (int j = 0; j < 25; ++j) {
            int i = cbase + j;
            if (i <= PP) PS[i] = run;
            run += v[j];
        }
    }
    __syncthreads();

    // ---- two key-space passes over the packed hist ----
    float acc = 0.f;
    unsigned below = 0;
    for (int p2 = 0; p2 < 2; ++p2) {
        const unsigned kbase = (unsigned)p2 << 15;

        for (int i = tid; i < 16384; i += 1024) hist[i] = 0u;
        __syncthreads();

        for (int j = 0; j < 24; ++j) {
            unsigned u = rowU[tid + j * 1024];
            unsigned rel = u - kbase;
            if (rel < 32768u) {
                unsigned wd = rel >> 1;
                atomicAdd(&hist[((wd & 15u) << 10) + (wd >> 4)],
                          1u << ((rel & 1u) << 4));
            }
        }
        __syncthreads();

        // scan: thread owns words w = tid*16+i (bins [32*tid, 32*tid+32))
        unsigned w[16];
        unsigned tsum = 0;
#pragma unroll
        for (int i = 0; i < 16; ++i) {
            w[i] = hist[(i << 10) + tid];
            tsum += (w[i] & 0xFFFFu) + (w[i] >> 16);
        }
        unsigned inc = tsum;
#pragma unroll
        for (int off = 1; off < 64; off <<= 1) {
            unsigned o = (unsigned)__shfl_up((int)inc, off, 64);
            if (lane >= off) inc += o;
        }
        if (lane == 63) wred[wave] = inc;
        __syncthreads();
        unsigned wbase = 0, tot = 0;
#pragma unroll
        for (int ww = 0; ww < 16; ++ww) {
            unsigned t = wred[ww];
            tot += t;
            wbase += (ww < wave) ? t : 0u;
        }

        unsigned running = below + wbase + (inc - tsum);
#pragma unroll
        for (int i = 0; i < 16; ++i) {
            unsigned binlo = kbase + (unsigned)tid * 32u + 2u * (unsigned)i;
            unsigned cl = w[i] & 0xFFFFu;
            if (cl) {
                unsigned r1 = min(running, (unsigned)PP);
                unsigned r2 = min(running + cl, (unsigned)PP);
                if (r1 < r2) {   // pads clamp to r1==r2; their decode is NaN
                    unsigned raw16 = (binlo & 0x8000u) ? (binlo & 0x7FFFu)
                                                       : ((~binlo) & 0xFFFFu);
                    acc += __uint_as_float(raw16 << 16) * (PS[r2] - PS[r1]);
                }
            }
            running += cl;
            unsigned ch = w[i] >> 16;
            if (ch) {
                unsigned binhi = binlo + 1u;
                unsigned r1 = min(running, (unsigned)PP);
                unsigned r2 = min(running + ch, (unsigned)PP);
                if (r1 < r2) {
                    unsigned raw16 = (binhi & 0x8000u) ? (binhi & 0x7FFFu)
                                                       : ((~binhi) & 0xFFFFu);
                    acc += __uint_as_float(raw16 << 16) * (PS[r2] - PS[r1]);
                }
            }
            running += ch;
        }
        below += tot;
        __syncthreads();   // protect hist zero / wred reuse across passes
    }

#pragma unroll
    for (int off = 32; off > 0; off >>= 1)
        acc += __shfl_down(acc, off, 64);
    if (lane == 0) fred[wave] = acc;
    __syncthreads();
    if (tid == 0) {
        float t = 0.f;
#pragma unroll
        for (int ww = 0; ww < 16; ++ww) t += fred[ww];
        out[k] = t;
    }
}

// ---------------------------------------------------------------------------
extern "C" void kernel_launch(void* const* d_in, const int* in_sizes, int n_in,
                              void* d_out, int out_size, void* d_ws, size_t ws_size,
                              hipStream_t stream) {
    const float* M      = (const float*)d_in[0];
    const float* Ws_in  = (const float*)d_in[1];
    const float* Wd_in  = (const float*)d_in[2];
    const float* Ws_out = (const float*)d_in[3];
    const float* Wd_out = (const float*)d_in[4];
    float* out = (float*)d_out;

    // workspace layout (18.4 MB):
    // [0, 9.36 MB):    vecB (PP x 192 bf16)
    // [9.36, 18.26):   sm2TP (181 x SNP u16 keys)
    // [18.26, +74KB):  Abf (192 x 192 bf16)
    char* ws = (char*)d_ws;
    ushort* vecB  = (ushort*)ws;
    ushort* sm2TP = (ushort*)(ws + (size_t)PP * VLD * 2);
    ushort* Abf   = (ushort*)(ws + (size_t)PP * VLD * 2 + (size_t)KK * SNP * 2);

    k_inner<<<512, 1024, 0, stream>>>(M, Ws_in, Wd_in, Ws_out, Abf, vecB);

    k_gemm<<<(SNP / 64) * 4, 256, 0, stream>>>(vecB, Abf, sm2TP);

    k_hist<<<KK, 1024, 0, stream>>>(sm2TP, Wd_out, out);
}

// Round 8
// 160.432 us; speedup vs baseline: 4.2176x; 1.0311x over previous
//
#include <hip/hip_runtime.h>
#include <hip/hip_bf16.h>

#define DIMK 3
#define NPTS 30
#define KK   181
#define PP   24360
#define DEMB 190
#define VLD  192   // padded vec row stride (bf16 elements)
#define SNP  24576 // logical sort-row length (16*1536)
#define SNPS 24608 // PADDED sm2TP row stride (+64B) — breaks 48KB power-of-2
                   // channel aliasing on k_gemm stores / k_hist row bases

typedef __attribute__((ext_vector_type(8))) short bf16x8;
typedef __attribute__((ext_vector_type(4))) float f32x4;
typedef __attribute__((ext_vector_type(2))) __fp16 h2;
typedef __attribute__((ext_vector_type(4))) ushort u16x4;
typedef __attribute__((ext_vector_type(4))) unsigned u32x4;

__device__ __forceinline__ ushort f2bf(float f) {
    unsigned u = __float_as_uint(f);
    u += 0x7FFFu + ((u >> 16) & 1u);
    return (ushort)(u >> 16);
}

// ---------------------------------------------------------------------------
// Kernel 1 [frozen r26]: packed-f16 pair sorting + wave-uniform scalarization.
// 56 us, VALU-bound (74%).
// ---------------------------------------------------------------------------
__global__ __launch_bounds__(1024, 2) void k_inner(
    const float* __restrict__ M,      // 3 x 30
    const float* __restrict__ Ws_in,  // 181 x 3
    const float* __restrict__ Wd_in,  // 181 x 27
    const float* __restrict__ Wout,   // 181 x 190
    ushort* __restrict__ Abf,         // 192 x 192 bf16 out
    ushort* __restrict__ vec)         // PP x VLD (bf16)
{
    __shared__ float Gs[NPTS * 32];
    __shared__ float WsS[192 * 3];
    __shared__ float WdS[192 * 28];

    const int tid = threadIdx.x;

    {
        int gid = blockIdx.x * 1024 + tid;
        if (gid < 192 * 192) {
            int k = gid / 192, d = gid - k * 192;
            Abf[gid] = (k < KK && d < DEMB) ? f2bf(Wout[k * DEMB + d]) : (ushort)0;
        }
    }

    for (int i = tid; i < 192 * 3; i += 1024) WsS[i] = (i < KK * 3) ? Ws_in[i] : 0.f;
    for (int i = tid; i < 192 * 28; i += 1024) {
        int k = i / 28, m = i - k * 28;
        WdS[i] = (k < KK && m < 27) ? Wd_in[k * 27 + m] : 0.f;
    }
    for (int e = tid; e < NPTS * 32; e += 1024) {
        int a = e >> 5, b = e & 31;
        Gs[e] = (b < NPTS)
            ? (M[a] * M[b] + M[NPTS + a] * M[NPTS + b] + M[2 * NPTS + a] * M[2 * NPTS + b])
            : 0.f;
    }
    __syncthreads();

    const int wave = __builtin_amdgcn_readfirstlane(tid >> 6);  // wave-uniform
    const int lane = tid & 63;
    const int wid = blockIdx.x * 16 + wave;   // 0..8191, uniform
    const int chunk = wid % 3;
    const int pstream = wid / 3;              // 0..2730
    const int nstream = (chunk == 2) ? 2730 : 2731;
    const int k = chunk * 64 + lane;

    const float INF = __builtin_inff();
    const bool kvalid = (k < KK);
    const float w0 = WsS[k * 3 + 0];
    const float w1 = WsS[k * 3 + 1];
    const float w2 = WsS[k * 3 + 2];
    const float* wd = WdS + k * 28;

    const int NPAIR = PP / 2;   // 12180

    for (int t = pstream; t < NPAIR; t += nstream) {
        const int p0 = 2 * t;                 // uniform
        int i0 = p0 / 812;                    // 812 = 29*28  (scalar magic-div)
        int r  = p0 - i0 * 812;
        int i1 = r / 28;
        int i2 = r - i1 * 28;
        int c0 = i0;
        int c1 = i1 + (i1 >= c0 ? 1 : 0);
        int lo = min(c0, c1), hi = max(c0, c1);
        int c2a = i2;
        if (c2a >= lo) c2a++;
        if (c2a >= hi) c2a++;
        int c2b = i2 + 1;
        if (c2b >= lo) c2b++;
        if (c2b >= hi) c2b++;

        ushort* vrow0 = vec + (long)p0 * VLD;
        ushort* vrow1 = vrow0 + VLD;

        if (chunk == 0 && lane < 9) {
            int i = lane / 3, j = lane % 3;
            int cia = (i == 0) ? c0 : ((i == 1) ? c1 : c2a);
            int cja = (j == 0) ? c0 : ((j == 1) ? c1 : c2a);
            vrow0[lane] = f2bf(Gs[(cia << 5) + cja]);
            int cib = (i == 0) ? c0 : ((i == 1) ? c1 : c2b);
            int cjb = (j == 0) ? c0 : ((j == 1) ? c1 : c2b);
            vrow1[lane] = f2bf(Gs[(cib << 5) + cjb]);
        }

        const float* g0 = Gs + (c0 << 5);
        const float* g1 = Gs + (c1 << 5);
        const float* ga = Gs + (c2a << 5);
        const float* gb = Gs + (c2b << 5);
        const unsigned basem = (1u << c0) | (1u << c1);   // uniform
        const unsigned maska = basem | (1u << c2a);       // uniform
        const unsigned maskb = basem | (1u << c2b);       // uniform

        h2 s[30];
#pragma unroll
        for (int q = 0; q < 8; ++q) {
            float4 x0 = *(const float4*)&g0[q * 4];
            float4 x1 = *(const float4*)&g1[q * 4];
            float4 xa = *(const float4*)&ga[q * 4];
            float4 xb = *(const float4*)&gb[q * 4];
            int j0 = q * 4;
            if (j0 + 0 < NPTS) {
                float c = w0 * x0.x + w1 * x1.x;
                float va = w2 * xa.x + c;
                float vb = w2 * xb.x + c;
                va = ((maska >> (j0 + 0)) & 1u) ? INF : va;
                vb = ((maskb >> (j0 + 0)) & 1u) ? INF : vb;
                s[j0 + 0] = __builtin_amdgcn_cvt_pkrtz(va, vb);
            }
            if (j0 + 1 < NPTS) {
                float c = w0 * x0.y + w1 * x1.y;
                float va = w2 * xa.y + c;
                float vb = w2 * xb.y + c;
                va = ((maska >> (j0 + 1)) & 1u) ? INF : va;
                vb = ((maskb >> (j0 + 1)) & 1u) ? INF : vb;
                s[j0 + 1] = __builtin_amdgcn_cvt_pkrtz(va, vb);
            }
            if (j0 + 2 < NPTS) {
                float c = w0 * x0.z + w1 * x1.z;
                float va = w2 * xa.z + c;
                float vb = w2 * xb.z + c;
                va = ((maska >> (j0 + 2)) & 1u) ? INF : va;
                vb = ((maskb >> (j0 + 2)) & 1u) ? INF : vb;
                s[j0 + 2] = __builtin_amdgcn_cvt_pkrtz(va, vb);
            }
            if (j0 + 3 < NPTS) {
                float c = w0 * x0.w + w1 * x1.w;
                float va = w2 * xa.w + c;
                float vb = w2 * xb.w + c;
                va = ((maska >> (j0 + 3)) & 1u) ? INF : va;
                vb = ((maskb >> (j0 + 3)) & 1u) ? INF : vb;
                s[j0 + 3] = __builtin_amdgcn_cvt_pkrtz(va, vb);
            }
        }

        // Batcher odd-even mergesort, pruned, packed pairs
#pragma unroll
        for (int pw = 1; pw < 32; pw <<= 1) {
#pragma unroll
            for (int kk = pw; kk >= 1; kk >>= 1) {
#pragma unroll
                for (int j = kk % pw; j + kk < 32; j += 2 * kk) {
#pragma unroll
                    for (int i = 0; i < kk; ++i) {
                        int a = i + j, b = i + j + kk;
                        if (a / (pw * 2) == b / (pw * 2) && b < 30
                            && !(pw == 16 && a == 27)) {
                            h2 x = s[a], y = s[b];
                            s[a] = __builtin_elementwise_min(x, y);
                            s[b] = __builtin_elementwise_max(x, y);
                        }
                    }
                }
            }
        }

        if (kvalid) {
            float emb0 = 0.f, emb1 = 0.f;
#pragma unroll
            for (int j = 0; j < 24; j += 4) {
                float4 w4 = *(const float4*)&wd[j];
                emb0 += w4.x * (float)s[j + 0].x + w4.y * (float)s[j + 1].x
                      + w4.z * (float)s[j + 2].x + w4.w * (float)s[j + 3].x;
                emb1 += w4.x * (float)s[j + 0].y + w4.y * (float)s[j + 1].y
                      + w4.z * (float)s[j + 2].y + w4.w * (float)s[j + 3].y;
            }
            {
                float4 w4 = *(const float4*)&wd[24];
                emb0 += w4.x * (float)s[24].x + w4.y * (float)s[25].x
                      + w4.z * (float)s[26].x;
                emb1 += w4.x * (float)s[24].y + w4.y * (float)s[25].y
                      + w4.z * (float)s[26].y;
            }
            vrow0[9 + k] = f2bf(emb0);
            vrow1[9 + k] = f2bf(emb1);
        } else if (k < 183) {
            vrow0[9 + k] = 0;
            vrow1[9 + k] = 0;
        }
    }
}

// ---------------------------------------------------------------------------
// Kernel 2 [r27 + SNPS stride]: grid 1536 (p-tile x kt-quarter, 256 thr),
// direct 16B global loads, swapped MFMA operands -> packed 8B stores.
// Only change: store stride SNPS (non-pow2-aligned rows).
// ---------------------------------------------------------------------------
__global__ __launch_bounds__(256) void k_gemm(
    const ushort* __restrict__ vecB,  // PP x 192 bf16
    const ushort* __restrict__ Abf,   // 192 x 192 bf16
    ushort* __restrict__ sm2TP)       // 181 x SNPS u16 encoded keys
{
    const int tid  = threadIdx.x;
    const int bid  = blockIdx.x;
    const int tile = bid >> 2;        // p-tile (64 p's)
    const int qtr  = bid & 3;         // kt quarter: 3 kt each
    const int wave = tid >> 6;
    const int lane = tid & 63;
    const int n = lane & 15;
    const int quad = lane >> 4;

    const int prow = tile * 64 + wave * 16 + n;
    bf16x8 afrag[6];
    {
        const ushort* row = vecB + (size_t)prow * VLD;
#pragma unroll
        for (int kc = 0; kc < 6; ++kc)
            afrag[kc] = *(const bf16x8*)&row[kc * 32 + quad * 8];
    }

    const int pb = tile * 64 + wave * 16 + quad * 4;  // lane's 4 consecutive p

#pragma unroll
    for (int i = 0; i < 3; ++i) {
        const int kt = qtr * 3 + i;
        const int kg = kt * 16 + n;
        f32x4 acc = {0.f, 0.f, 0.f, 0.f};
        const ushort* arow = Abf + kg * 192;
#pragma unroll
        for (int kc = 0; kc < 6; ++kc) {
            bf16x8 bfrag = *(const bf16x8*)&arow[kc * 32 + quad * 8];
            acc = __builtin_amdgcn_mfma_f32_16x16x32_bf16(afrag[kc], bfrag, acc, 0, 0, 0);
        }
        if (kg < KK) {
            u16x4 st;
#pragma unroll
            for (int r = 0; r < 4; ++r) {
                int p = pb + r;
                unsigned e;
                if (p < PP) {
                    unsigned u = __float_as_uint(acc[r]);
                    u = (u & 0x80000000u) ? ~u : (u | 0x80000000u);
                    e = (u + 0x8000u) >> 16;     // RTN 16-bit monotone key
                } else {
                    e = 0xFFFFu;                 // pad sorts strictly last
                }
                st[r] = (ushort)e;
            }
            *(u16x4*)&sm2TP[(size_t)kg * SNPS + pb] = st;  // 8B aligned
        }
    }
}

// ---------------------------------------------------------------------------
// Kernel 3 (r29): RANK-SCATTER. One block per k (grid 181, one round).
// Drops r28's PS array + per-bin dot. Phases:
//  1. keys -> registers (6 x u16x4 coalesced)
//  2. two key-space passes (32768 bins each, u16-packed hist, 64KB):
//     count atomics -> block CDF scan (transposed slots, conflict-free) ->
//     per-ELEMENT rank = packed atomicAdd -> sv[rank] = bf16 bits (u16 LDS).
//     All 24576 elements (incl. 216 pads at ranks >= PP) write sv exactly once.
//  3. final dot, fully coalesced: acc += wrow[i] (float4, HBM) *
//     decode(sv[i]) (u16x4, LDS); tail i >= PP skipped (24360 % 4 == 0 ->
//     clean whole-vector cut at tid 970, pads/NaN bits never touched).
// LDS 64 + 48 KB = 112.5 KB -> 1 block/CU. Ranks <= 24576 < 2^15: packed
// u16 halves never carry. Equal keys: distinct ranks, same value -> exact.
// ---------------------------------------------------------------------------
__global__ __launch_bounds__(1024, 1) void k_hist(
    const ushort* __restrict__ sm2TP,    // 181 x SNPS u16 keys (padded)
    const float* __restrict__ WdOut,     // 181 x PP
    float* __restrict__ out)             // 181
{
    __shared__ unsigned hist[16384];     // 64 KiB (u16-packed, 32768 bins/pass)
    __shared__ ushort sv[SNP];           // 48 KiB rank-indexed value bits
    __shared__ unsigned wred[16];
    __shared__ float fred[16];

    const int tid  = threadIdx.x;
    const int wave = tid >> 6;
    const int lane = tid & 63;
    const int k    = blockIdx.x;

    const ushort* rowU = sm2TP + (size_t)k * SNPS;
    const float* wrow  = WdOut + (size_t)k * PP;

    // keys -> registers, coalesced 8B loads
    u16x4 kv[6];
#pragma unroll
    for (int j = 0; j < 6; ++j)
        kv[j] = *(const u16x4*)&rowU[tid * 4 + j * 4096];

    unsigned below = 0;
    for (int p2 = 0; p2 < 2; ++p2) {
        const unsigned kbase = (unsigned)p2 << 15;

        for (int i = tid; i < 4096; i += 1024)
            ((u32x4*)hist)[i] = (u32x4){0u, 0u, 0u, 0u};
        __syncthreads();

        // count
#pragma unroll
        for (int j = 0; j < 6; ++j) {
#pragma unroll
            for (int e = 0; e < 4; ++e) {
                unsigned u = kv[j][e];
                unsigned rel = u - kbase;
                if (rel < 32768u) {
                    unsigned wd = rel >> 1;
                    atomicAdd(&hist[((wd & 15u) << 10) + (wd >> 4)],
                              1u << ((rel & 1u) << 4));
                }
            }
        }
        __syncthreads();

        // CDF scan: thread owns transposed words (i<<10)+tid = bins
        // [32*tid, 32*tid+32)
        unsigned w[16];
        unsigned tsum = 0;
#pragma unroll
        for (int i = 0; i < 16; ++i) {
            w[i] = hist[(i << 10) + tid];
            tsum += (w[i] & 0xFFFFu) + (w[i] >> 16);
        }
        unsigned inc = tsum;
#pragma unroll
        for (int off = 1; off < 64; off <<= 1) {
            unsigned o = (unsigned)__shfl_up((int)inc, off, 64);
            if (lane >= off) inc += o;
        }
        if (lane == 63) wred[wave] = inc;
        __syncthreads();
        unsigned wbase = 0, tot = 0;
#pragma unroll
        for (int ww = 0; ww < 16; ++ww) {
            unsigned t = wred[ww];
            tot += t;
            wbase += (ww < wave) ? t : 0u;
        }

        unsigned running = below + wbase + (inc - tsum);
#pragma unroll
        for (int i = 0; i < 16; ++i) {
            unsigned lob = running;
            running += (w[i] & 0xFFFFu);
            unsigned hib = running;
            running += (w[i] >> 16);
            hist[(i << 10) + tid] = lob | (hib << 16);   // own words only
        }
        __syncthreads();

        // per-element rank + scatter value bits
#pragma unroll
        for (int j = 0; j < 6; ++j) {
#pragma unroll
            for (int e = 0; e < 4; ++e) {
                unsigned u = kv[j][e];
                unsigned rel = u - kbase;
                if (rel < 32768u) {
                    unsigned wd = rel >> 1;
                    unsigned sh = (rel & 1u) << 4;
                    unsigned old = atomicAdd(&hist[((wd & 15u) << 10) + (wd >> 4)],
                                             1u << sh);
                    unsigned r = (old >> sh) & 0xFFFFu;
                    unsigned raw16 = (u & 0x8000u) ? (u & 0x7FFFu)
                                                   : ((~u) & 0xFFFFu);
                    sv[r] = (ushort)raw16;
                }
            }
        }
        below += tot;
        __syncthreads();
    }

    // coalesced fused dot
    float acc = 0.f;
#pragma unroll
    for (int j = 0; j < 6; ++j) {
        int i4 = tid * 4 + j * 4096;
        if (i4 < PP) {   // PP % 4 == 0: whole-vector cut, no partials
            u16x4 s4 = *(const u16x4*)&sv[i4];
            float4 w4 = *(const float4*)&wrow[i4];
            acc += w4.x * __uint_as_float((unsigned)s4[0] << 16)
                 + w4.y * __uint_as_float((unsigned)s4[1] << 16)
                 + w4.z * __uint_as_float((unsigned)s4[2] << 16)
                 + w4.w * __uint_as_float((unsigned)s4[3] << 16);
        }
    }

#pragma unroll
    for (int off = 32; off > 0; off >>= 1)
        acc += __shfl_down(acc, off, 64);
    if (lane == 0) fred[wave] = acc;
    __syncthreads();
    if (tid == 0) {
        float t = 0.f;
#pragma unroll
        for (int ww = 0; ww < 16; ++ww) t += fred[ww];
        out[k] = t;
    }
}

// ---------------------------------------------------------------------------
extern "C" void kernel_launch(void* const* d_in, const int* in_sizes, int n_in,
                              void* d_out, int out_size, void* d_ws, size_t ws_size,
                              hipStream_t stream) {
    const float* M      = (const float*)d_in[0];
    const float* Ws_in  = (const float*)d_in[1];
    const float* Wd_in  = (const float*)d_in[2];
    const float* Ws_out = (const float*)d_in[3];
    const float* Wd_out = (const float*)d_in[4];
    float* out = (float*)d_out;

    // workspace layout (~18.4 MB), Abf moved before sm2TP:
    // [0, 9.36 MB):        vecB (PP x 192 bf16)
    // [9.36, +74KB):       Abf (192 x 192 bf16)
    // [9.43, +8.91 MB):    sm2TP (181 x SNPS u16 keys)
    char* ws = (char*)d_ws;
    ushort* vecB  = (ushort*)ws;
    ushort* Abf   = (ushort*)(ws + (size_t)PP * VLD * 2);
    ushort* sm2TP = (ushort*)(ws + (size_t)PP * VLD * 2 + (size_t)192 * 192 * 2);

    k_inner<<<512, 1024, 0, stream>>>(M, Ws_in, Wd_in, Ws_out, Abf, vecB);

    k_gemm<<<(SNP / 64) * 4, 256, 0, stream>>>(vecB, Abf, sm2TP);

    k_hist<<<KK, 1024, 0, stream>>>(sm2TP, Wd_out, out);
}